// Round 8
// baseline (915.664 us; speedup 1.0000x reference)
//
#include <hip/hip_runtime.h>

// B=4, T=4096, D=A=1024.  All-MFMA bf16 pipeline, BK=64 async staging:
//   to_bf16  : X,Wq,Wk,Wv fp32 -> bf16 (stored in d_out, dead until o_gemm)
//   proj_qk  : Q,K bf16 row-major; XCD-swizzled (2048 blocks)
//   s_gemm_v : packed lower-tri S = Q.K^T/32 (all batches) + V-projection
//              tiles in the dead upper-triangle slots (writes Vt[b][a][t])
//   softmax  : in-place rows of packed S -> P bf16, zero-padded to ld
//   o_gemm   : out = P.Vt^T, variable K, y-interleaved for balance
// Packed S: row-block y at elem offset y(y+1)/2*16384, leading dim (y+1)*128.
// LDS: row stride 64 elems; data col c of row stored at c ^ sw(row),
// sw(row) = ((row&1)<<5)|(((row>>1)&3)<<3)  (applied to the GLOBAL source col
// at staging -- DMA dest must stay lane*16B -- and XORed back at frag read).
// R8: __launch_bounds__(256,5) on GEMM kernels -> VGPR cap 102 -> 5 blocks/CU
// (LDS 32KB allows exactly 5; round-7 VGPR=116 limited residency to 4 waves/
// SIMD, leaving MfmaUtil at 23% with 58% of cycles idle on barrier drains).
// ws: Q 32MB | K 32MB | Vt 32MB | S G*17.3MB   (G from ws_size)
// d_out (64MB) doubles as Xb(32MB)+Wb(6MB) scratch during projection.

#define T_SEQ 4096
#define DA    1024
#define BATCH 4
#define M_TOT (BATCH * T_SEQ)            // 16384
#define SB_ELEMS 8650752                  // 528 tri-blocks * 16384 elems

typedef float  f32x4  __attribute__((ext_vector_type(4)));
typedef short  bf16x8 __attribute__((ext_vector_type(8)));

static __device__ __forceinline__ unsigned short f2bf(float f) {
    unsigned u = __builtin_bit_cast(unsigned, f);
    u += 0x7FFFu + ((u >> 16) & 1u);      // RNE
    return (unsigned short)(u >> 16);
}
static __device__ __forceinline__ unsigned pack2(float a, float b) {
    return (unsigned)f2bf(a) | ((unsigned)f2bf(b) << 16);
}
static __device__ __forceinline__ float bflo(unsigned u) {
    return __builtin_bit_cast(float, u << 16);
}
static __device__ __forceinline__ float bfhi(unsigned u) {
    return __builtin_bit_cast(float, u & 0xFFFF0000u);
}

// async global->LDS, 16 B per lane; LDS dest = wave-uniform base + lane*16
#define GLOAD_LDS16(g, l)                                                   \
    __builtin_amdgcn_global_load_lds(                                       \
        (const __attribute__((address_space(1))) void*)(g),                 \
        (__attribute__((address_space(3))) void*)(l), 16, 0, 0)

// ---------------------------------------------------------------------------
// BK=64 K-loop: 128x64 bf16 tiles, async staging, 32 MFMA per iteration.
// ---------------------------------------------------------------------------
static __device__ __forceinline__ void gemm_k_loop64(
    const unsigned short* __restrict__ A, int lda,
    const unsigned short* __restrict__ B, int ldb,
    int m0, int n0, int K,
    unsigned short* __restrict__ Xs, unsigned short* __restrict__ Ws,
    int tid, int wm, int wn, int qq, int r, int swz, f32x4 acc[4][4])
{
    const int srow = tid >> 3;                              // 0..31
    const int scg  = ((tid & 7) * 8)
                   ^ ((srow & 1) << 5) ^ (((srow >> 1) & 3) << 3);
    const unsigned short* ga = A + (size_t)(m0 + srow) * lda + scg;
    const unsigned short* gb = B + (size_t)(n0 + srow) * ldb + scg;
    unsigned short* la = Xs + tid * 8;                      // lane*16B dest
    unsigned short* lb = Ws + tid * 8;

    for (int k0 = 0; k0 < K; k0 += 64) {
        #pragma unroll
        for (int p = 0; p < 4; ++p) {
            GLOAD_LDS16(ga + (size_t)(32 * p) * lda + k0, la + p * 2048);
            GLOAD_LDS16(gb + (size_t)(32 * p) * ldb + k0, lb + p * 2048);
        }
        __syncthreads();
        #pragma unroll
        for (int h = 0; h < 2; ++h) {
            const int co = (h * 32 + qq * 8) ^ swz;
            bf16x8 a[4], b[4];
            #pragma unroll
            for (int i = 0; i < 4; ++i)
                a[i] = *(const bf16x8*)&Xs[(wm * 64 + i * 16 + r) * 64 + co];
            #pragma unroll
            for (int j = 0; j < 4; ++j)
                b[j] = *(const bf16x8*)&Ws[(wn * 64 + j * 16 + r) * 64 + co];
            #pragma unroll
            for (int i = 0; i < 4; ++i)
                #pragma unroll
                for (int j = 0; j < 4; ++j)
                    acc[i][j] = __builtin_amdgcn_mfma_f32_16x16x32_bf16(
                        a[i], b[j], acc[i][j], 0, 0, 0);
        }
        __syncthreads();
    }
}

#define GEMM_PROLOGUE                                                        \
    __shared__ unsigned short Xs[8192];                                      \
    __shared__ unsigned short Ws[8192];                                      \
    const int tid  = threadIdx.x;                                            \
    const int wave = tid >> 6;                                               \
    const int lane = tid & 63;                                               \
    const int wm   = wave >> 1;                                              \
    const int wn   = wave & 1;                                               \
    const int qq   = lane >> 4;                                              \
    const int r    = lane & 15;                                              \
    const int swz  = ((r & 1) << 5) | (((r >> 1) & 3) << 3);                 \
    f32x4 acc[4][4];                                                         \
    _Pragma("unroll")                                                        \
    for (int i = 0; i < 4; ++i)                                              \
        _Pragma("unroll")                                                    \
        for (int j = 0; j < 4; ++j)                                          \
            acc[i][j] = f32x4{0.f, 0.f, 0.f, 0.f};

// C/D layout: col = lane&15, row = (lane>>4)*4 + reg
#define EPILOGUE_LOOP(BODY)                                                  \
    _Pragma("unroll")                                                        \
    for (int i = 0; i < 4; ++i)                                              \
        _Pragma("unroll")                                                    \
        for (int j = 0; j < 4; ++j)                                          \
            _Pragma("unroll")                                                \
            for (int rr = 0; rr < 4; ++rr) {                                 \
                const int row = wm * 64 + i * 16 + qq * 4 + rr;              \
                const int col = wn * 64 + j * 16 + r;                        \
                const float val = acc[i][j][rr];                             \
                BODY                                                         \
            }

// transposed V epilogue: rows rg0..rg0+3 are consecutive t -> one ushort4
#define EPILOGUE_VT(VT, M0, NC)                                              \
    _Pragma("unroll")                                                        \
    for (int i = 0; i < 4; ++i)                                              \
        _Pragma("unroll")                                                    \
        for (int j = 0; j < 4; ++j) {                                        \
            const int rg0 = (M0) + wm * 64 + i * 16 + qq * 4;                \
            const int col = wn * 64 + j * 16 + r;                            \
            const int bb  = rg0 >> 12;                                       \
            const int tt  = rg0 & 4095;                                      \
            ushort4 pkv;                                                     \
            pkv.x = f2bf(acc[i][j][0]); pkv.y = f2bf(acc[i][j][1]);          \
            pkv.z = f2bf(acc[i][j][2]); pkv.w = f2bf(acc[i][j][3]);          \
            *(ushort4*)&(VT)[((size_t)bb << 22) +                            \
                             (size_t)((NC) + col) * 4096 + tt] = pkv;        \
        }

// ---------------------------------------------------------------------------
// fp32 -> bf16 conversion. Blocks 0..8191: X. Blocks 8192..9727: Wq|Wk|Wv.
// ---------------------------------------------------------------------------
__global__ __launch_bounds__(256) void to_bf16_all(
    const float* __restrict__ X, const float* __restrict__ Wq,
    const float* __restrict__ Wk, const float* __restrict__ Wv,
    unsigned short* __restrict__ Xb, unsigned short* __restrict__ Wb)
{
    const int bx = blockIdx.x;
    const float* src;
    unsigned short* dst;
    size_t off;
    if (bx < 8192) {
        src = X; dst = Xb; off = (size_t)bx * 2048;
    } else {
        const int s   = bx - 8192;
        const int seg = s >> 9;
        src = (seg == 0) ? Wq : (seg == 1) ? Wk : Wv;
        dst = Wb + (size_t)seg * (DA * DA);
        off = (size_t)(s & 511) * 2048;
    }
    const size_t i = off + (size_t)threadIdx.x * 8;
    const float4 v0 = *(const float4*)(src + i);
    const float4 v1 = *(const float4*)(src + i + 4);
    uint4 pk;
    pk.x = pack2(v0.x, v0.y); pk.y = pack2(v0.z, v0.w);
    pk.z = pack2(v1.x, v1.y); pk.w = pack2(v1.z, v1.w);
    *(uint4*)(dst + i) = pk;
}

// ---------------------------------------------------------------------------
// Q,K projections. Wb = [3*1024][1024] (Wq|Wk|Wv). 2048 blocks, XCD-swizzled.
// ---------------------------------------------------------------------------
__global__ __launch_bounds__(256, 5) void proj_qk(
    const unsigned short* __restrict__ Xb, const unsigned short* __restrict__ Wb,
    unsigned short* __restrict__ qb, unsigned short* __restrict__ kb)
{
    const int li   = blockIdx.x;
    const int xcd  = li & 7;
    const int slot = li >> 3;            // 0..255
    const int mt   = xcd * 16 + (slot >> 4);
    const int nt   = slot & 15;          // 0..15 across Wq|Wk
    const int m0   = mt * 128;

    GEMM_PROLOGUE
    gemm_k_loop64(Xb, DA, Wb, DA, m0, nt * 128, DA, Xs, Ws,
                  tid, wm, wn, qq, r, swz, acc);

    unsigned short* Y = (nt >> 3) ? kb : qb;
    const int nc = (nt & 7) * 128;
    EPILOGUE_LOOP({
        Y[(size_t)(m0 + row) * DA + (nc + col)] = f2bf(val);
    })
}

// ---------------------------------------------------------------------------
// Fallback V projection (used only if workspace forces G<4).
// ---------------------------------------------------------------------------
__global__ __launch_bounds__(256, 5) void proj_v(
    const unsigned short* __restrict__ Xb, const unsigned short* __restrict__ Wb,
    unsigned short* __restrict__ vt)
{
    const int li = blockIdx.x;           // 0..1023
    const int mt = li >> 3;
    const int nt = li & 7;
    const int m0 = mt * 128;
    GEMM_PROLOGUE
    gemm_k_loop64(Xb, DA, Wb + (size_t)2048 * DA, DA, m0, nt * 128, DA, Xs, Ws,
                  tid, wm, wn, qq, r, swz, acc);
    EPILOGUE_VT(vt, m0, nt * 128)
}

// ---------------------------------------------------------------------------
// S = Q.K^T / 32 (lower-tri, packed) with V-projection tiles on the dead
// upper-triangle slots. grid (32, 32, G). Single prologue, one 32KB LDS set.
// ---------------------------------------------------------------------------
__global__ __launch_bounds__(256, 5) void s_gemm_v(
    const unsigned short* __restrict__ qb, const unsigned short* __restrict__ kb,
    const unsigned short* __restrict__ Xb, const unsigned short* __restrict__ Wb,
    unsigned short* __restrict__ sbuf, unsigned short* __restrict__ vt,
    int bbase, int vPerZ)
{
    const int yr = 31 - (int)blockIdx.y;
    const int x  = blockIdx.x;
    const int bz = blockIdx.z;
    const bool isS = (x <= yr);

    const unsigned short *Am, *Bm;
    int m0, n0;
    if (isS) {
        const int b = bbase + bz;
        Am = qb + (size_t)b * T_SEQ * DA;
        Bm = kb + (size_t)b * T_SEQ * DA;
        m0 = yr * 128;
        n0 = x * 128;
    } else {
        const int u = x * (x - 1) / 2 + yr;
        if (u >= vPerZ) return;
        const int vid = bz * vPerZ + u;      // 0..1023
        Am = Xb;
        Bm = Wb + (size_t)2048 * DA;
        m0 = (vid >> 3) * 128;
        n0 = (vid & 7) * 128;
    }

    GEMM_PROLOGUE
    gemm_k_loop64(Am, DA, Bm, DA, m0, n0, DA, Xs, Ws,
                  tid, wm, wn, qq, r, swz, acc);

    if (isS) {
        const int ld = (yr + 1) * 128;
        unsigned short* base = sbuf + (size_t)bz * SB_ELEMS
                             + (size_t)(yr * (yr + 1) / 2) * 16384;
        EPILOGUE_LOOP({
            base[(size_t)row * ld + (n0 + col)] = f2bf(val * 0.03125f);
        })
    } else {
        EPILOGUE_VT(vt, m0, n0)
    }
}

// ---------------------------------------------------------------------------
// Row softmax on packed S. grid (4096, G); big rows first.
// ---------------------------------------------------------------------------
__global__ __launch_bounds__(256) void softmax_rows(unsigned short* __restrict__ sbuf)
{
    __shared__ float row[4096];
    __shared__ float red[4];
    const int q   = 4095 - (int)blockIdx.x;
    const int n   = q + 1;
    const int tid = threadIdx.x;
    const int y   = q >> 7;
    const int ld  = (y + 1) * 128;
    unsigned short* rp = sbuf + (size_t)blockIdx.y * SB_ELEMS
                       + (size_t)(y * (y + 1) / 2) * 16384
                       + (size_t)(q & 127) * ld;
    const int n8 = n & ~7;

    for (int i0 = tid * 8; i0 < n8; i0 += 2048) {
        const uint4 v = *(const uint4*)(rp + i0);
        *(float4*)&row[i0]     = make_float4(bflo(v.x), bfhi(v.x), bflo(v.y), bfhi(v.y));
        *(float4*)&row[i0 + 4] = make_float4(bflo(v.z), bfhi(v.z), bflo(v.w), bfhi(v.w));
    }
    for (int i = n8 + tid; i < n; i += 256)
        row[i] = __builtin_bit_cast(float, (unsigned)rp[i] << 16);
    __syncthreads();

    float m = -1e30f;
    for (int i = tid; i < n; i += 256) m = fmaxf(m, row[i]);
    #pragma unroll
    for (int off = 32; off >= 1; off >>= 1) m = fmaxf(m, __shfl_xor(m, off, 64));
    if ((tid & 63) == 0) red[tid >> 6] = m;
    __syncthreads();
    m = fmaxf(fmaxf(red[0], red[1]), fmaxf(red[2], red[3]));
    __syncthreads();

    float s = 0.f;
    for (int i = tid; i < n; i += 256) {
        const float e = __expf(row[i] - m);
        row[i] = e;
        s += e;
    }
    #pragma unroll
    for (int off = 32; off >= 1; off >>= 1) s += __shfl_xor(s, off, 64);
    if ((tid & 63) == 0) red[tid >> 6] = s;
    __syncthreads();
    s = red[0] + red[1] + red[2] + red[3];
    const float inv = 1.f / s;

    for (int i0 = tid * 8; i0 < n8; i0 += 2048) {
        const float4 f0 = *(const float4*)&row[i0];
        const float4 f1 = *(const float4*)&row[i0 + 4];
        uint4 pk;
        pk.x = pack2(f0.x * inv, f0.y * inv);
        pk.y = pack2(f0.z * inv, f0.w * inv);
        pk.z = pack2(f1.x * inv, f1.y * inv);
        pk.w = pack2(f1.z * inv, f1.w * inv);
        *(uint4*)(rp + i0) = pk;
    }
    for (int i = n8 + tid; i < ld; i += 256)
        rp[i] = (i < n) ? f2bf(row[i] * inv) : (unsigned short)0;
}

// ---------------------------------------------------------------------------
// out = P.Vt^T, K = (y+1)*128. grid (8, 32, G).
// y interleaved 31,0,30,1,... so resident blocks per CU mix big/small K.
// ---------------------------------------------------------------------------
__global__ __launch_bounds__(256, 5) void o_gemm(
    const unsigned short* __restrict__ sbuf, const unsigned short* __restrict__ vt,
    float* __restrict__ out, int bbase)
{
    const int gy = blockIdx.y;
    const int y  = (gy & 1) ? (gy >> 1) : (31 - (gy >> 1));
    const int b  = bbase + blockIdx.z;
    const int K_len = (y + 1) * 128;
    const unsigned short* A  = sbuf + (size_t)blockIdx.z * SB_ELEMS
                             + (size_t)(y * (y + 1) / 2) * 16384;
    const unsigned short* Bv = vt + (size_t)b * T_SEQ * DA;   // [1024][4096]
    const int n0 = blockIdx.x * 128;

    GEMM_PROLOGUE
    gemm_k_loop64(A, K_len, Bv, T_SEQ, 0, n0, K_len, Xs, Ws,
                  tid, wm, wn, qq, r, swz, acc);

    float* outb = out + (size_t)b * T_SEQ * DA + (size_t)y * 128 * DA;
    EPILOGUE_LOOP({
        outb[(size_t)row * DA + (n0 + col)] = rintf(val * 1e4f) * 1e-4f;
    })
}

// ---------------------------------------------------------------------------
extern "C" void kernel_launch(void* const* d_in, const int* in_sizes, int n_in,
                              void* d_out, int out_size, void* d_ws, size_t ws_size,
                              hipStream_t stream)
{
    const float* X  = (const float*)d_in[0];
    const float* Wq = (const float*)d_in[1];
    const float* Wk = (const float*)d_in[2];
    const float* Wv = (const float*)d_in[3];
    float* out = (float*)d_out;

    unsigned short* qb   = (unsigned short*)d_ws;          // [16384,1024]
    unsigned short* kb   = qb + (size_t)M_TOT * DA;
    unsigned short* vt   = kb + (size_t)M_TOT * DA;        // [4][1024][4096]
    unsigned short* sbuf = vt + (size_t)M_TOT * DA;        // G * SB_ELEMS

    // bf16 copies of X / W live in d_out (64 MB), dead until o_gemm writes.
    unsigned short* Xb = (unsigned short*)d_out;           // 32 MB
    unsigned short* Wb = Xb + (size_t)M_TOT * DA;          // 6 MB ([3*1024][1024])

    const size_t fixed = (size_t)3 * M_TOT * DA * 2;
    int G = 1;
    if (ws_size >= fixed + (size_t)4 * SB_ELEMS * 2) G = 4;
    else if (ws_size >= fixed + (size_t)2 * SB_ELEMS * 2) G = 2;

    to_bf16_all<<<9728, 256, 0, stream>>>(X, Wq, Wk, Wv, Xb, Wb);
    proj_qk<<<2048, 256, 0, stream>>>(Xb, Wb, qb, kb);
    if (G < 4)
        proj_v<<<1024, 256, 0, stream>>>(Xb, Wb, vt);

    for (int b0 = 0; b0 < BATCH; b0 += G) {
        const int vPerZ = (G == 4) ? 256 : 0;   // V fused only in the G=4 path
        s_gemm_v<<<dim3(32, 32, G), 256, 0, stream>>>(
            qb, kb, Xb, Wb, sbuf, vt, b0, vPerZ);
        softmax_rows<<<dim3(4096, G), 256, 0, stream>>>(sbuf);
        o_gemm<<<dim3(8, 32, G), 256, 0, stream>>>(sbuf, vt, out, b0);
    }
}

// Round 9
// 536.373 us; speedup vs baseline: 1.7071x; 1.7071x over previous
//
#include <hip/hip_runtime.h>

// B=4, T=4096, D=A=1024.  All-MFMA bf16 pipeline, BK=64 async staging:
//   to_bf16  : X,Wq,Wk,Wv fp32 -> bf16 (stored in d_out, dead until o_gemm)
//   proj_qk  : Q,K bf16 row-major; XCD-swizzled (2048 blocks)
//   s_gemm_v : packed lower-tri S = Q.K^T/32 (all batches) + V-projection
//              tiles in the dead upper-triangle slots (writes Vt[b][a][t])
//   softmax  : in-place rows of packed S -> P bf16, zero-padded to ld
//   o_gemm   : out = P.Vt^T, variable K, y-interleaved for balance
// Packed S: row-block y at elem offset y(y+1)/2*16384, leading dim (y+1)*128.
// LDS: row stride 64 elems; data col c of row stored at c ^ sw(row),
// sw(row) = ((row&1)<<5)|(((row>>1)&3)<<3)  (applied to the GLOBAL source col
// at staging -- DMA dest must stay lane*16B -- and XORed back at frag read).
// Residual SQ_LDS_BANK_CONFLICT (~4.1e3/block) is the DMA-write floor
// (128 wave-writes x 32 banks), not fragment reads -- LDS reads are clean.
// R9: REVERTED __launch_bounds__(256,5) -- the VGPR cap 102 made the
// allocator spill the whole 64-reg accumulator (r8: VGPR=48, WRITE_SIZE
// 290MB scratch, 915us). Occupancy must come from structural VGPR cuts:
// K-loop DMA addressing now uses 2 loop-carried pointers + sequential
// += 32*ld increments instead of 8 hoisted pointer pairs.
// ws: Q 32MB | K 32MB | Vt 32MB | S G*17.3MB   (G from ws_size)
// d_out (64MB) doubles as Xb(32MB)+Wb(6MB) scratch during projection.

#define T_SEQ 4096
#define DA    1024
#define BATCH 4
#define M_TOT (BATCH * T_SEQ)            // 16384
#define SB_ELEMS 8650752                  // 528 tri-blocks * 16384 elems

typedef float  f32x4  __attribute__((ext_vector_type(4)));
typedef short  bf16x8 __attribute__((ext_vector_type(8)));

static __device__ __forceinline__ unsigned short f2bf(float f) {
    unsigned u = __builtin_bit_cast(unsigned, f);
    u += 0x7FFFu + ((u >> 16) & 1u);      // RNE
    return (unsigned short)(u >> 16);
}
static __device__ __forceinline__ unsigned pack2(float a, float b) {
    return (unsigned)f2bf(a) | ((unsigned)f2bf(b) << 16);
}
static __device__ __forceinline__ float bflo(unsigned u) {
    return __builtin_bit_cast(float, u << 16);
}
static __device__ __forceinline__ float bfhi(unsigned u) {
    return __builtin_bit_cast(float, u & 0xFFFF0000u);
}

// async global->LDS, 16 B per lane; LDS dest = wave-uniform base + lane*16
#define GLOAD_LDS16(g, l)                                                   \
    __builtin_amdgcn_global_load_lds(                                       \
        (const __attribute__((address_space(1))) void*)(g),                 \
        (__attribute__((address_space(3))) void*)(l), 16, 0, 0)

// ---------------------------------------------------------------------------
// BK=64 K-loop: 128x64 bf16 tiles, async staging, 32 MFMA per iteration.
// Loop-carried pointer increments (not 8 hoisted pointer pairs) to keep
// VGPR pressure down.
// ---------------------------------------------------------------------------
static __device__ __forceinline__ void gemm_k_loop64(
    const unsigned short* __restrict__ A, int lda,
    const unsigned short* __restrict__ B, int ldb,
    int m0, int n0, int K,
    unsigned short* __restrict__ Xs, unsigned short* __restrict__ Ws,
    int tid, int wm, int wn, int qq, int r, int swz, f32x4 acc[4][4])
{
    const int srow = tid >> 3;                              // 0..31
    const int scg  = ((tid & 7) * 8)
                   ^ ((srow & 1) << 5) ^ (((srow >> 1) & 3) << 3);
    const unsigned short* ga = A + (size_t)(m0 + srow) * lda + scg;
    const unsigned short* gb = B + (size_t)(n0 + srow) * ldb + scg;
    unsigned short* la = Xs + tid * 8;                      // lane*16B dest
    unsigned short* lb = Ws + tid * 8;
    const size_t astep = (size_t)32 * lda;
    const size_t bstep = (size_t)32 * ldb;

    for (int k0 = 0; k0 < K; k0 += 64) {
        const unsigned short* pa = ga;
        const unsigned short* pb = gb;
        #pragma unroll
        for (int p = 0; p < 4; ++p) {
            GLOAD_LDS16(pa, la + p * 2048);
            GLOAD_LDS16(pb, lb + p * 2048);
            pa += astep;
            pb += bstep;
        }
        ga += 64;
        gb += 64;
        __syncthreads();
        #pragma unroll
        for (int h = 0; h < 2; ++h) {
            const int co = (h * 32 + qq * 8) ^ swz;
            bf16x8 a[4], b[4];
            #pragma unroll
            for (int i = 0; i < 4; ++i)
                a[i] = *(const bf16x8*)&Xs[(wm * 64 + i * 16 + r) * 64 + co];
            #pragma unroll
            for (int j = 0; j < 4; ++j)
                b[j] = *(const bf16x8*)&Ws[(wn * 64 + j * 16 + r) * 64 + co];
            #pragma unroll
            for (int i = 0; i < 4; ++i)
                #pragma unroll
                for (int j = 0; j < 4; ++j)
                    acc[i][j] = __builtin_amdgcn_mfma_f32_16x16x32_bf16(
                        a[i], b[j], acc[i][j], 0, 0, 0);
        }
        __syncthreads();
    }
}

#define GEMM_PROLOGUE                                                        \
    __shared__ unsigned short Xs[8192];                                      \
    __shared__ unsigned short Ws[8192];                                      \
    const int tid  = threadIdx.x;                                            \
    const int wave = tid >> 6;                                               \
    const int lane = tid & 63;                                               \
    const int wm   = wave >> 1;                                              \
    const int wn   = wave & 1;                                               \
    const int qq   = lane >> 4;                                              \
    const int r    = lane & 15;                                              \
    const int swz  = ((r & 1) << 5) | (((r >> 1) & 3) << 3);                 \
    f32x4 acc[4][4];                                                         \
    _Pragma("unroll")                                                        \
    for (int i = 0; i < 4; ++i)                                              \
        _Pragma("unroll")                                                    \
        for (int j = 0; j < 4; ++j)                                          \
            acc[i][j] = f32x4{0.f, 0.f, 0.f, 0.f};

// C/D layout: col = lane&15, row = (lane>>4)*4 + reg
#define EPILOGUE_LOOP(BODY)                                                  \
    _Pragma("unroll")                                                        \
    for (int i = 0; i < 4; ++i)                                              \
        _Pragma("unroll")                                                    \
        for (int j = 0; j < 4; ++j)                                          \
            _Pragma("unroll")                                                \
            for (int rr = 0; rr < 4; ++rr) {                                 \
                const int row = wm * 64 + i * 16 + qq * 4 + rr;              \
                const int col = wn * 64 + j * 16 + r;                        \
                const float val = acc[i][j][rr];                             \
                BODY                                                         \
            }

// transposed V epilogue: rows rg0..rg0+3 are consecutive t -> one ushort4
#define EPILOGUE_VT(VT, M0, NC)                                              \
    _Pragma("unroll")                                                        \
    for (int i = 0; i < 4; ++i)                                              \
        _Pragma("unroll")                                                    \
        for (int j = 0; j < 4; ++j) {                                        \
            const int rg0 = (M0) + wm * 64 + i * 16 + qq * 4;                \
            const int col = wn * 64 + j * 16 + r;                            \
            const int bb  = rg0 >> 12;                                       \
            const int tt  = rg0 & 4095;                                      \
            ushort4 pkv;                                                     \
            pkv.x = f2bf(acc[i][j][0]); pkv.y = f2bf(acc[i][j][1]);          \
            pkv.z = f2bf(acc[i][j][2]); pkv.w = f2bf(acc[i][j][3]);          \
            *(ushort4*)&(VT)[((size_t)bb << 22) +                            \
                             (size_t)((NC) + col) * 4096 + tt] = pkv;        \
        }

// ---------------------------------------------------------------------------
// fp32 -> bf16 conversion. Blocks 0..8191: X. Blocks 8192..9727: Wq|Wk|Wv.
// ---------------------------------------------------------------------------
__global__ __launch_bounds__(256) void to_bf16_all(
    const float* __restrict__ X, const float* __restrict__ Wq,
    const float* __restrict__ Wk, const float* __restrict__ Wv,
    unsigned short* __restrict__ Xb, unsigned short* __restrict__ Wb)
{
    const int bx = blockIdx.x;
    const float* src;
    unsigned short* dst;
    size_t off;
    if (bx < 8192) {
        src = X; dst = Xb; off = (size_t)bx * 2048;
    } else {
        const int s   = bx - 8192;
        const int seg = s >> 9;
        src = (seg == 0) ? Wq : (seg == 1) ? Wk : Wv;
        dst = Wb + (size_t)seg * (DA * DA);
        off = (size_t)(s & 511) * 2048;
    }
    const size_t i = off + (size_t)threadIdx.x * 8;
    const float4 v0 = *(const float4*)(src + i);
    const float4 v1 = *(const float4*)(src + i + 4);
    uint4 pk;
    pk.x = pack2(v0.x, v0.y); pk.y = pack2(v0.z, v0.w);
    pk.z = pack2(v1.x, v1.y); pk.w = pack2(v1.z, v1.w);
    *(uint4*)(dst + i) = pk;
}

// ---------------------------------------------------------------------------
// Q,K projections. Wb = [3*1024][1024] (Wq|Wk|Wv). 2048 blocks, XCD-swizzled.
// ---------------------------------------------------------------------------
__global__ __launch_bounds__(256) void proj_qk(
    const unsigned short* __restrict__ Xb, const unsigned short* __restrict__ Wb,
    unsigned short* __restrict__ qb, unsigned short* __restrict__ kb)
{
    const int li   = blockIdx.x;
    const int xcd  = li & 7;
    const int slot = li >> 3;            // 0..255
    const int mt   = xcd * 16 + (slot >> 4);
    const int nt   = slot & 15;          // 0..15 across Wq|Wk
    const int m0   = mt * 128;

    GEMM_PROLOGUE
    gemm_k_loop64(Xb, DA, Wb, DA, m0, nt * 128, DA, Xs, Ws,
                  tid, wm, wn, qq, r, swz, acc);

    unsigned short* Y = (nt >> 3) ? kb : qb;
    const int nc = (nt & 7) * 128;
    EPILOGUE_LOOP({
        Y[(size_t)(m0 + row) * DA + (nc + col)] = f2bf(val);
    })
}

// ---------------------------------------------------------------------------
// Fallback V projection (used only if workspace forces G<4).
// ---------------------------------------------------------------------------
__global__ __launch_bounds__(256) void proj_v(
    const unsigned short* __restrict__ Xb, const unsigned short* __restrict__ Wb,
    unsigned short* __restrict__ vt)
{
    const int li = blockIdx.x;           // 0..1023
    const int mt = li >> 3;
    const int nt = li & 7;
    const int m0 = mt * 128;
    GEMM_PROLOGUE
    gemm_k_loop64(Xb, DA, Wb + (size_t)2048 * DA, DA, m0, nt * 128, DA, Xs, Ws,
                  tid, wm, wn, qq, r, swz, acc);
    EPILOGUE_VT(vt, m0, nt * 128)
}

// ---------------------------------------------------------------------------
// S = Q.K^T / 32 (lower-tri, packed) with V-projection tiles on the dead
// upper-triangle slots. grid (32, 32, G). Single prologue, one 32KB LDS set.
// ---------------------------------------------------------------------------
__global__ __launch_bounds__(256) void s_gemm_v(
    const unsigned short* __restrict__ qb, const unsigned short* __restrict__ kb,
    const unsigned short* __restrict__ Xb, const unsigned short* __restrict__ Wb,
    unsigned short* __restrict__ sbuf, unsigned short* __restrict__ vt,
    int bbase, int vPerZ)
{
    const int yr = 31 - (int)blockIdx.y;
    const int x  = blockIdx.x;
    const int bz = blockIdx.z;
    const bool isS = (x <= yr);

    const unsigned short *Am, *Bm;
    int m0, n0;
    if (isS) {
        const int b = bbase + bz;
        Am = qb + (size_t)b * T_SEQ * DA;
        Bm = kb + (size_t)b * T_SEQ * DA;
        m0 = yr * 128;
        n0 = x * 128;
    } else {
        const int u = x * (x - 1) / 2 + yr;
        if (u >= vPerZ) return;
        const int vid = bz * vPerZ + u;      // 0..1023
        Am = Xb;
        Bm = Wb + (size_t)2048 * DA;
        m0 = (vid >> 3) * 128;
        n0 = (vid & 7) * 128;
    }

    GEMM_PROLOGUE
    gemm_k_loop64(Am, DA, Bm, DA, m0, n0, DA, Xs, Ws,
                  tid, wm, wn, qq, r, swz, acc);

    if (isS) {
        const int ld = (yr + 1) * 128;
        unsigned short* base = sbuf + (size_t)bz * SB_ELEMS
                             + (size_t)(yr * (yr + 1) / 2) * 16384;
        EPILOGUE_LOOP({
            base[(size_t)row * ld + (n0 + col)] = f2bf(val * 0.03125f);
        })
    } else {
        EPILOGUE_VT(vt, m0, n0)
    }
}

// ---------------------------------------------------------------------------
// Row softmax on packed S. grid (4096, G); big rows first.
// ---------------------------------------------------------------------------
__global__ __launch_bounds__(256) void softmax_rows(unsigned short* __restrict__ sbuf)
{
    __shared__ float row[4096];
    __shared__ float red[4];
    const int q   = 4095 - (int)blockIdx.x;
    const int n   = q + 1;
    const int tid = threadIdx.x;
    const int y   = q >> 7;
    const int ld  = (y + 1) * 128;
    unsigned short* rp = sbuf + (size_t)blockIdx.y * SB_ELEMS
                       + (size_t)(y * (y + 1) / 2) * 16384
                       + (size_t)(q & 127) * ld;
    const int n8 = n & ~7;

    for (int i0 = tid * 8; i0 < n8; i0 += 2048) {
        const uint4 v = *(const uint4*)(rp + i0);
        *(float4*)&row[i0]     = make_float4(bflo(v.x), bfhi(v.x), bflo(v.y), bfhi(v.y));
        *(float4*)&row[i0 + 4] = make_float4(bflo(v.z), bfhi(v.z), bflo(v.w), bfhi(v.w));
    }
    for (int i = n8 + tid; i < n; i += 256)
        row[i] = __builtin_bit_cast(float, (unsigned)rp[i] << 16);
    __syncthreads();

    float m = -1e30f;
    for (int i = tid; i < n; i += 256) m = fmaxf(m, row[i]);
    #pragma unroll
    for (int off = 32; off >= 1; off >>= 1) m = fmaxf(m, __shfl_xor(m, off, 64));
    if ((tid & 63) == 0) red[tid >> 6] = m;
    __syncthreads();
    m = fmaxf(fmaxf(red[0], red[1]), fmaxf(red[2], red[3]));
    __syncthreads();

    float s = 0.f;
    for (int i = tid; i < n; i += 256) {
        const float e = __expf(row[i] - m);
        row[i] = e;
        s += e;
    }
    #pragma unroll
    for (int off = 32; off >= 1; off >>= 1) s += __shfl_xor(s, off, 64);
    if ((tid & 63) == 0) red[tid >> 6] = s;
    __syncthreads();
    s = red[0] + red[1] + red[2] + red[3];
    const float inv = 1.f / s;

    for (int i0 = tid * 8; i0 < n8; i0 += 2048) {
        const float4 f0 = *(const float4*)&row[i0];
        const float4 f1 = *(const float4*)&row[i0 + 4];
        uint4 pk;
        pk.x = pack2(f0.x * inv, f0.y * inv);
        pk.y = pack2(f0.z * inv, f0.w * inv);
        pk.z = pack2(f1.x * inv, f1.y * inv);
        pk.w = pack2(f1.z * inv, f1.w * inv);
        *(uint4*)(rp + i0) = pk;
    }
    for (int i = n8 + tid; i < ld; i += 256)
        rp[i] = (i < n) ? f2bf(row[i] * inv) : (unsigned short)0;
}

// ---------------------------------------------------------------------------
// out = P.Vt^T, K = (y+1)*128. grid (8, 32, G).
// y interleaved 31,0,30,1,... so resident blocks per CU mix big/small K.
// ---------------------------------------------------------------------------
__global__ __launch_bounds__(256) void o_gemm(
    const unsigned short* __restrict__ sbuf, const unsigned short* __restrict__ vt,
    float* __restrict__ out, int bbase)
{
    const int gy = blockIdx.y;
    const int y  = (gy & 1) ? (gy >> 1) : (31 - (gy >> 1));
    const int b  = bbase + blockIdx.z;
    const int K_len = (y + 1) * 128;
    const unsigned short* A  = sbuf + (size_t)blockIdx.z * SB_ELEMS
                             + (size_t)(y * (y + 1) / 2) * 16384;
    const unsigned short* Bv = vt + (size_t)b * T_SEQ * DA;   // [1024][4096]
    const int n0 = blockIdx.x * 128;

    GEMM_PROLOGUE
    gemm_k_loop64(A, K_len, Bv, T_SEQ, 0, n0, K_len, Xs, Ws,
                  tid, wm, wn, qq, r, swz, acc);

    float* outb = out + (size_t)b * T_SEQ * DA + (size_t)y * 128 * DA;
    EPILOGUE_LOOP({
        outb[(size_t)row * DA + (n0 + col)] = rintf(val * 1e4f) * 1e-4f;
    })
}

// ---------------------------------------------------------------------------
extern "C" void kernel_launch(void* const* d_in, const int* in_sizes, int n_in,
                              void* d_out, int out_size, void* d_ws, size_t ws_size,
                              hipStream_t stream)
{
    const float* X  = (const float*)d_in[0];
    const float* Wq = (const float*)d_in[1];
    const float* Wk = (const float*)d_in[2];
    const float* Wv = (const float*)d_in[3];
    float* out = (float*)d_out;

    unsigned short* qb   = (unsigned short*)d_ws;          // [16384,1024]
    unsigned short* kb   = qb + (size_t)M_TOT * DA;
    unsigned short* vt   = kb + (size_t)M_TOT * DA;        // [4][1024][4096]
    unsigned short* sbuf = vt + (size_t)M_TOT * DA;        // G * SB_ELEMS

    // bf16 copies of X / W live in d_out (64 MB), dead until o_gemm writes.
    unsigned short* Xb = (unsigned short*)d_out;           // 32 MB
    unsigned short* Wb = Xb + (size_t)M_TOT * DA;          // 6 MB ([3*1024][1024])

    const size_t fixed = (size_t)3 * M_TOT * DA * 2;
    int G = 1;
    if (ws_size >= fixed + (size_t)4 * SB_ELEMS * 2) G = 4;
    else if (ws_size >= fixed + (size_t)2 * SB_ELEMS * 2) G = 2;

    to_bf16_all<<<9728, 256, 0, stream>>>(X, Wq, Wk, Wv, Xb, Wb);
    proj_qk<<<2048, 256, 0, stream>>>(Xb, Wb, qb, kb);
    if (G < 4)
        proj_v<<<1024, 256, 0, stream>>>(Xb, Wb, vt);

    for (int b0 = 0; b0 < BATCH; b0 += G) {
        const int vPerZ = (G == 4) ? 256 : 0;   // V fused only in the G=4 path
        s_gemm_v<<<dim3(32, 32, G), 256, 0, stream>>>(
            qb, kb, Xb, Wb, sbuf, vt, b0, vPerZ);
        softmax_rows<<<dim3(4096, G), 256, 0, stream>>>(sbuf);
        o_gemm<<<dim3(8, 32, G), 256, 0, stream>>>(sbuf, vt, out, b0);
    }
}

// Round 10
// 509.125 us; speedup vs baseline: 1.7985x; 1.0535x over previous
//
#include <hip/hip_runtime.h>

// B=4, T=4096, D=A=1024.  All-MFMA bf16 pipeline, BK=64 async staging.
//   to_bf16  : X,Wq,Wk,Wv fp32 -> bf16 (stored in d_out, dead until o_gemm)
//   proj_qk  : Q,K bf16; 256x128 tiles, 512 thr, XCD-swizzled (1024 blocks)
//   s_gemm_v : packed lower-tri S = Q.K^T/32 (all batches) + V-projection
//              tiles on dead upper-tri slots (writes Vt[b][a][t]).
//              R10: 256x128 tiles / 512 threads -- 2x MFMA work per barrier
//              window (r9: 44% issue-busy, 56% stalled on per-barrier DMA
//              drains; doubling per-block work per barrier halves drain rate
//              per FLOP at the same 16 waves/CU).
//   softmax  : in-place rows of packed S -> P bf16, zero-padded to ld
//   o_gemm   : out = P.Vt^T, 128x128 (packed-S ld varies mid-256-tile)
// Packed S: row-block y128 at elem offset y128(y128+1)/2*16384, ld (y128+1)*128.
// LDS: row stride 64 elems; col c of row stored at c ^ sw(row),
// sw(row)=((row&1)<<5)|(((row>>1)&3)<<3), applied to the GLOBAL source col at
// staging (DMA dest must stay lane*16B) and XORed back at fragment read.
// ws: Q 32MB | K 32MB | Vt 32MB | S G*17.3MB   (G from ws_size)
// d_out (64MB) doubles as Xb(32MB)+Wb(6MB) scratch during projection.

#define T_SEQ 4096
#define DA    1024
#define BATCH 4
#define M_TOT (BATCH * T_SEQ)            // 16384
#define SB_ELEMS 8650752                  // 528 tri-blocks * 16384 elems

typedef float  f32x4  __attribute__((ext_vector_type(4)));
typedef short  bf16x8 __attribute__((ext_vector_type(8)));

static __device__ __forceinline__ unsigned short f2bf(float f) {
    unsigned u = __builtin_bit_cast(unsigned, f);
    u += 0x7FFFu + ((u >> 16) & 1u);      // RNE
    return (unsigned short)(u >> 16);
}
static __device__ __forceinline__ unsigned pack2(float a, float b) {
    return (unsigned)f2bf(a) | ((unsigned)f2bf(b) << 16);
}
static __device__ __forceinline__ float bflo(unsigned u) {
    return __builtin_bit_cast(float, u << 16);
}
static __device__ __forceinline__ float bfhi(unsigned u) {
    return __builtin_bit_cast(float, u & 0xFFFF0000u);
}

// async global->LDS, 16 B per lane; LDS dest = wave-uniform base + lane*16
#define GLOAD_LDS16(g, l)                                                   \
    __builtin_amdgcn_global_load_lds(                                       \
        (const __attribute__((address_space(1))) void*)(g),                 \
        (__attribute__((address_space(3))) void*)(l), 16, 0, 0)

// ---------------------------------------------------------------------------
// MFMA core (shared): per wave 64x64 out of Xs rows [wm*64,+64), Ws [wn*64,+64)
// ---------------------------------------------------------------------------
static __device__ __forceinline__ void mfma_step(
    const unsigned short* __restrict__ Xs, const unsigned short* __restrict__ Ws,
    int wm, int wn, int qq, int r, int swz, f32x4 acc[4][4])
{
    #pragma unroll
    for (int h = 0; h < 2; ++h) {
        const int co = (h * 32 + qq * 8) ^ swz;
        bf16x8 a[4], b[4];
        #pragma unroll
        for (int i = 0; i < 4; ++i)
            a[i] = *(const bf16x8*)&Xs[(wm * 64 + i * 16 + r) * 64 + co];
        #pragma unroll
        for (int j = 0; j < 4; ++j)
            b[j] = *(const bf16x8*)&Ws[(wn * 64 + j * 16 + r) * 64 + co];
        #pragma unroll
        for (int i = 0; i < 4; ++i)
            #pragma unroll
            for (int j = 0; j < 4; ++j)
                acc[i][j] = __builtin_amdgcn_mfma_f32_16x16x32_bf16(
                    a[i], b[j], acc[i][j], 0, 0, 0);
    }
}

// ---------------------------------------------------------------------------
// 256-thread K-loop: 128x64 A + 128x64 B tiles (o_gemm).
// ---------------------------------------------------------------------------
static __device__ __forceinline__ void k_loop_256(
    const unsigned short* __restrict__ A, int lda,
    const unsigned short* __restrict__ B, int ldb,
    int m0, int n0, int K,
    unsigned short* __restrict__ Xs, unsigned short* __restrict__ Ws,
    int tid, int wm, int wn, int qq, int r, int swz, f32x4 acc[4][4])
{
    const int srow = tid >> 3;                              // 0..31
    const int scg  = ((tid & 7) * 8)
                   ^ ((srow & 1) << 5) ^ (((srow >> 1) & 3) << 3);
    const unsigned short* ga = A + (size_t)(m0 + srow) * lda + scg;
    const unsigned short* gb = B + (size_t)(n0 + srow) * ldb + scg;
    unsigned short* la = Xs + tid * 8;
    unsigned short* lb = Ws + tid * 8;
    const size_t astep = (size_t)32 * lda;
    const size_t bstep = (size_t)32 * ldb;

    for (int k0 = 0; k0 < K; k0 += 64) {
        const unsigned short* pa = ga;
        const unsigned short* pb = gb;
        #pragma unroll
        for (int p = 0; p < 4; ++p) {
            GLOAD_LDS16(pa, la + p * 2048);
            GLOAD_LDS16(pb, lb + p * 2048);
            pa += astep;
            pb += bstep;
        }
        ga += 64;
        gb += 64;
        __syncthreads();
        mfma_step(Xs, Ws, wm, wn, qq, r, swz, acc);
        __syncthreads();
    }
}

// ---------------------------------------------------------------------------
// 512-thread K-loop: 256x64 A + 128x64 B tiles (proj/s_gemm_v).
// ---------------------------------------------------------------------------
static __device__ __forceinline__ void k_loop_512(
    const unsigned short* __restrict__ A, int lda,
    const unsigned short* __restrict__ B, int ldb,
    int m0, int n0, int K,
    unsigned short* __restrict__ Xs, unsigned short* __restrict__ Ws,
    int tid, int wm, int wn, int qq, int r, int swz, f32x4 acc[4][4])
{
    const int srow = tid >> 3;                              // 0..63
    const int scg  = ((tid & 7) * 8)
                   ^ ((srow & 1) << 5) ^ (((srow >> 1) & 3) << 3);
    const unsigned short* ga = A + (size_t)(m0 + srow) * lda + scg;
    const unsigned short* gb = B + (size_t)(n0 + srow) * ldb + scg;
    unsigned short* la = Xs + tid * 8;
    unsigned short* lb = Ws + tid * 8;
    const size_t astep = (size_t)64 * lda;
    const size_t bstep = (size_t)64 * ldb;

    for (int k0 = 0; k0 < K; k0 += 64) {
        const unsigned short* pa = ga;
        #pragma unroll
        for (int p = 0; p < 4; ++p) {           // A: 4 x 64 rows = 256
            GLOAD_LDS16(pa, la + p * 4096);
            pa += astep;
        }
        const unsigned short* pb = gb;
        #pragma unroll
        for (int p = 0; p < 2; ++p) {           // B: 2 x 64 rows = 128
            GLOAD_LDS16(pb, lb + p * 4096);
            pb += bstep;
        }
        ga += 64;
        gb += 64;
        __syncthreads();
        mfma_step(Xs, Ws, wm, wn, qq, r, swz, acc);
        __syncthreads();
    }
}

#define GEMM_VARS                                                            \
    const int tid  = threadIdx.x;                                            \
    const int wave = tid >> 6;                                               \
    const int lane = tid & 63;                                               \
    const int wm   = wave >> 1;                                              \
    const int wn   = wave & 1;                                               \
    const int qq   = lane >> 4;                                              \
    const int r    = lane & 15;                                              \
    const int swz  = ((r & 1) << 5) | (((r >> 1) & 3) << 3);                 \
    f32x4 acc[4][4];                                                         \
    _Pragma("unroll")                                                        \
    for (int i = 0; i < 4; ++i)                                              \
        _Pragma("unroll")                                                    \
        for (int j = 0; j < 4; ++j)                                          \
            acc[i][j] = f32x4{0.f, 0.f, 0.f, 0.f};

#define GEMM_PROLOGUE_256                                                    \
    __shared__ unsigned short Xs[8192];                                      \
    __shared__ unsigned short Ws[8192];                                      \
    GEMM_VARS

#define GEMM_PROLOGUE_512                                                    \
    __shared__ unsigned short Xs[16384];                                     \
    __shared__ unsigned short Ws[8192];                                      \
    GEMM_VARS

// C/D layout: col = lane&15, row = (lane>>4)*4 + reg   (row within wave tile)
#define EPILOGUE_LOOP(BODY)                                                  \
    _Pragma("unroll")                                                        \
    for (int i = 0; i < 4; ++i)                                              \
        _Pragma("unroll")                                                    \
        for (int j = 0; j < 4; ++j)                                          \
            _Pragma("unroll")                                                \
            for (int rr = 0; rr < 4; ++rr) {                                 \
                const int row = wm * 64 + i * 16 + qq * 4 + rr;              \
                const int col = wn * 64 + j * 16 + r;                        \
                const float val = acc[i][j][rr];                             \
                BODY                                                         \
            }

// transposed V epilogue: rows rg0..rg0+3 are consecutive t -> one ushort4
#define EPILOGUE_VT(VT, M0, NC)                                              \
    _Pragma("unroll")                                                        \
    for (int i = 0; i < 4; ++i)                                              \
        _Pragma("unroll")                                                    \
        for (int j = 0; j < 4; ++j) {                                        \
            const int rg0 = (M0) + wm * 64 + i * 16 + qq * 4;                \
            const int col = wn * 64 + j * 16 + r;                            \
            const int bb  = rg0 >> 12;                                       \
            const int tt  = rg0 & 4095;                                      \
            ushort4 pkv;                                                     \
            pkv.x = f2bf(acc[i][j][0]); pkv.y = f2bf(acc[i][j][1]);          \
            pkv.z = f2bf(acc[i][j][2]); pkv.w = f2bf(acc[i][j][3]);          \
            *(ushort4*)&(VT)[((size_t)bb << 22) +                            \
                             (size_t)((NC) + col) * 4096 + tt] = pkv;        \
        }

// ---------------------------------------------------------------------------
// fp32 -> bf16 conversion. Blocks 0..8191: X. Blocks 8192..9727: Wq|Wk|Wv.
// ---------------------------------------------------------------------------
__global__ __launch_bounds__(256) void to_bf16_all(
    const float* __restrict__ X, const float* __restrict__ Wq,
    const float* __restrict__ Wk, const float* __restrict__ Wv,
    unsigned short* __restrict__ Xb, unsigned short* __restrict__ Wb)
{
    const int bx = blockIdx.x;
    const float* src;
    unsigned short* dst;
    size_t off;
    if (bx < 8192) {
        src = X; dst = Xb; off = (size_t)bx * 2048;
    } else {
        const int s   = bx - 8192;
        const int seg = s >> 9;
        src = (seg == 0) ? Wq : (seg == 1) ? Wk : Wv;
        dst = Wb + (size_t)seg * (DA * DA);
        off = (size_t)(s & 511) * 2048;
    }
    const size_t i = off + (size_t)threadIdx.x * 8;
    const float4 v0 = *(const float4*)(src + i);
    const float4 v1 = *(const float4*)(src + i + 4);
    uint4 pk;
    pk.x = pack2(v0.x, v0.y); pk.y = pack2(v0.z, v0.w);
    pk.z = pack2(v1.x, v1.y); pk.w = pack2(v1.z, v1.w);
    *(uint4*)(dst + i) = pk;
}

// ---------------------------------------------------------------------------
// Q,K projections, 256x128 tiles. Wb = [3*1024][1024]. 1024 blocks,
// XCD-swizzled: xcd owns mt band [xcd*8, xcd*8+8), n fastest.
// ---------------------------------------------------------------------------
__global__ __launch_bounds__(512) void proj_qk(
    const unsigned short* __restrict__ Xb, const unsigned short* __restrict__ Wb,
    unsigned short* __restrict__ qb, unsigned short* __restrict__ kb)
{
    const int li   = blockIdx.x;
    const int xcd  = li & 7;
    const int slot = li >> 3;            // 0..127
    const int mt   = xcd * 8 + (slot >> 4);
    const int nt   = slot & 15;          // 0..15 across Wq|Wk
    const int m0   = mt * 256;

    GEMM_PROLOGUE_512
    k_loop_512(Xb, DA, Wb, DA, m0, nt * 128, DA, Xs, Ws,
               tid, wm, wn, qq, r, swz, acc);

    unsigned short* Y = (nt >> 3) ? kb : qb;
    const int nc = (nt & 7) * 128;
    EPILOGUE_LOOP({
        Y[(size_t)(m0 + row) * DA + (nc + col)] = f2bf(val);
    })
}

// ---------------------------------------------------------------------------
// Fallback V projection (only if workspace forces G<4). 512 blocks, 256x128.
// ---------------------------------------------------------------------------
__global__ __launch_bounds__(512) void proj_v(
    const unsigned short* __restrict__ Xb, const unsigned short* __restrict__ Wb,
    unsigned short* __restrict__ vt)
{
    const int li = blockIdx.x;           // 0..511
    const int m0 = (li >> 3) * 256;
    const int n0 = (li & 7) * 128;
    GEMM_PROLOGUE_512
    k_loop_512(Xb, DA, Wb + (size_t)2048 * DA, DA, m0, n0, DA, Xs, Ws,
               tid, wm, wn, qq, r, swz, acc);
    EPILOGUE_VT(vt, m0, n0)
}

// ---------------------------------------------------------------------------
// S = Q.K^T / 32 (lower-tri, packed) with V tiles on dead upper slots.
// grid (32, 16, G), 512 threads, 256x128 tiles.
// S tile (yr, x) active iff x <= 2*yr+1. Rows span packed blocks 2yr, 2yr+1
// (different ld) -> per-element y128/ld; col guard drops the dead half of the
// boundary tile x == 2yr+1.
// Upper slot u = yr*(31-yr) + (x - 2yr - 2)  (x > 2yr+1), u < vPerZ -> V tile.
// ---------------------------------------------------------------------------
__global__ __launch_bounds__(512) void s_gemm_v(
    const unsigned short* __restrict__ qb, const unsigned short* __restrict__ kb,
    const unsigned short* __restrict__ Xb, const unsigned short* __restrict__ Wb,
    unsigned short* __restrict__ sbuf, unsigned short* __restrict__ vt,
    int bbase, int vPerZ)
{
    const int yr = 15 - (int)blockIdx.y;
    const int x  = blockIdx.x;
    const int bz = blockIdx.z;
    const bool isS = (x <= 2 * yr + 1);

    const unsigned short *Am, *Bm;
    int m0, n0;
    if (isS) {
        const int b = bbase + bz;
        Am = qb + (size_t)b * T_SEQ * DA;
        Bm = kb + (size_t)b * T_SEQ * DA;
        m0 = yr * 256;
        n0 = x * 128;
    } else {
        const int u = yr * (31 - yr) + (x - 2 * yr - 2);
        if (u >= vPerZ) return;
        const int vid = bz * vPerZ + u;      // 0..511
        Am = Xb;
        Bm = Wb + (size_t)2048 * DA;
        m0 = (vid >> 3) * 256;
        n0 = (vid & 7) * 128;
    }

    GEMM_PROLOGUE_512
    k_loop_512(Am, DA, Bm, DA, m0, n0, DA, Xs, Ws,
               tid, wm, wn, qq, r, swz, acc);

    if (isS) {
        unsigned short* Sz = sbuf + (size_t)bz * SB_ELEMS;
        EPILOGUE_LOOP({
            const int grow = m0 + row;
            const int y128 = grow >> 7;
            const int ld   = (y128 + 1) * 128;
            const int colg = n0 + col;
            if (colg < ld)
                Sz[(size_t)(y128 * (y128 + 1) / 2) * 16384
                   + (size_t)(grow & 127) * ld + colg] = f2bf(val * 0.03125f);
        })
    } else {
        EPILOGUE_VT(vt, m0, n0)
    }
}

// ---------------------------------------------------------------------------
// Row softmax on packed S. grid (4096, G); big rows first.
// ---------------------------------------------------------------------------
__global__ __launch_bounds__(256) void softmax_rows(unsigned short* __restrict__ sbuf)
{
    __shared__ float row[4096];
    __shared__ float red[4];
    const int q   = 4095 - (int)blockIdx.x;
    const int n   = q + 1;
    const int tid = threadIdx.x;
    const int y   = q >> 7;
    const int ld  = (y + 1) * 128;
    unsigned short* rp = sbuf + (size_t)blockIdx.y * SB_ELEMS
                       + (size_t)(y * (y + 1) / 2) * 16384
                       + (size_t)(q & 127) * ld;
    const int n8 = n & ~7;

    for (int i0 = tid * 8; i0 < n8; i0 += 2048) {
        const uint4 v = *(const uint4*)(rp + i0);
        *(float4*)&row[i0]     = make_float4(bflo(v.x), bfhi(v.x), bflo(v.y), bfhi(v.y));
        *(float4*)&row[i0 + 4] = make_float4(bflo(v.z), bfhi(v.z), bflo(v.w), bfhi(v.w));
    }
    for (int i = n8 + tid; i < n; i += 256)
        row[i] = __builtin_bit_cast(float, (unsigned)rp[i] << 16);
    __syncthreads();

    float m = -1e30f;
    for (int i = tid; i < n; i += 256) m = fmaxf(m, row[i]);
    #pragma unroll
    for (int off = 32; off >= 1; off >>= 1) m = fmaxf(m, __shfl_xor(m, off, 64));
    if ((tid & 63) == 0) red[tid >> 6] = m;
    __syncthreads();
    m = fmaxf(fmaxf(red[0], red[1]), fmaxf(red[2], red[3]));
    __syncthreads();

    float s = 0.f;
    for (int i = tid; i < n; i += 256) {
        const float e = __expf(row[i] - m);
        row[i] = e;
        s += e;
    }
    #pragma unroll
    for (int off = 32; off >= 1; off >>= 1) s += __shfl_xor(s, off, 64);
    if ((tid & 63) == 0) red[tid >> 6] = s;
    __syncthreads();
    s = red[0] + red[1] + red[2] + red[3];
    const float inv = 1.f / s;

    for (int i0 = tid * 8; i0 < n8; i0 += 2048) {
        const float4 f0 = *(const float4*)&row[i0];
        const float4 f1 = *(const float4*)&row[i0 + 4];
        uint4 pk;
        pk.x = pack2(f0.x * inv, f0.y * inv);
        pk.y = pack2(f0.z * inv, f0.w * inv);
        pk.z = pack2(f1.x * inv, f1.y * inv);
        pk.w = pack2(f1.z * inv, f1.w * inv);
        *(uint4*)(rp + i0) = pk;
    }
    for (int i = n8 + tid; i < ld; i += 256)
        rp[i] = (i < n) ? f2bf(row[i] * inv) : (unsigned short)0;
}

// ---------------------------------------------------------------------------
// out = P.Vt^T, K = (y+1)*128. grid (8, 32, G), 256 threads, 128x128.
// y interleaved 31,0,30,1,... so resident blocks per CU mix big/small K.
// ---------------------------------------------------------------------------
__global__ __launch_bounds__(256) void o_gemm(
    const unsigned short* __restrict__ sbuf, const unsigned short* __restrict__ vt,
    float* __restrict__ out, int bbase)
{
    const int gy = blockIdx.y;
    const int y  = (gy & 1) ? (gy >> 1) : (31 - (gy >> 1));
    const int b  = bbase + blockIdx.z;
    const int K_len = (y + 1) * 128;
    const unsigned short* A  = sbuf + (size_t)blockIdx.z * SB_ELEMS
                             + (size_t)(y * (y + 1) / 2) * 16384;
    const unsigned short* Bv = vt + (size_t)b * T_SEQ * DA;   // [1024][4096]
    const int n0 = blockIdx.x * 128;

    GEMM_PROLOGUE_256
    k_loop_256(A, K_len, Bv, T_SEQ, 0, n0, K_len, Xs, Ws,
               tid, wm, wn, qq, r, swz, acc);

    float* outb = out + (size_t)b * T_SEQ * DA + (size_t)y * 128 * DA;
    EPILOGUE_LOOP({
        outb[(size_t)row * DA + (n0 + col)] = rintf(val * 1e4f) * 1e-4f;
    })
}

// ---------------------------------------------------------------------------
extern "C" void kernel_launch(void* const* d_in, const int* in_sizes, int n_in,
                              void* d_out, int out_size, void* d_ws, size_t ws_size,
                              hipStream_t stream)
{
    const float* X  = (const float*)d_in[0];
    const float* Wq = (const float*)d_in[1];
    const float* Wk = (const float*)d_in[2];
    const float* Wv = (const float*)d_in[3];
    float* out = (float*)d_out;

    unsigned short* qb   = (unsigned short*)d_ws;          // [16384,1024]
    unsigned short* kb   = qb + (size_t)M_TOT * DA;
    unsigned short* vt   = kb + (size_t)M_TOT * DA;        // [4][1024][4096]
    unsigned short* sbuf = vt + (size_t)M_TOT * DA;        // G * SB_ELEMS

    // bf16 copies of X / W live in d_out (64 MB), dead until o_gemm writes.
    unsigned short* Xb = (unsigned short*)d_out;           // 32 MB
    unsigned short* Wb = Xb + (size_t)M_TOT * DA;          // 6 MB ([3*1024][1024])

    const size_t fixed = (size_t)3 * M_TOT * DA * 2;
    int G = 1;
    if (ws_size >= fixed + (size_t)4 * SB_ELEMS * 2) G = 4;
    else if (ws_size >= fixed + (size_t)2 * SB_ELEMS * 2) G = 2;

    to_bf16_all<<<9728, 256, 0, stream>>>(X, Wq, Wk, Wv, Xb, Wb);
    proj_qk<<<1024, 512, 0, stream>>>(Xb, Wb, qb, kb);
    if (G < 4)
        proj_v<<<512, 512, 0, stream>>>(Xb, Wb, vt);

    for (int b0 = 0; b0 < BATCH; b0 += G) {
        const int vPerZ = (G == 4) ? 128 : 0;   // V fused only in the G=4 path
        s_gemm_v<<<dim3(32, 16, G), 512, 0, stream>>>(
            qb, kb, Xb, Wb, sbuf, vt, b0, vPerZ);
        softmax_rows<<<dim3(4096, G), 256, 0, stream>>>(sbuf);
        o_gemm<<<dim3(8, 32, G), 256, 0, stream>>>(sbuf, vt, out, b0);
    }
}